// Round 1
// baseline (1598.095 us; speedup 1.0000x reference)
//
#include <hip/hip_runtime.h>
#include <hip/hip_bf16.h>
#include <cstddef>

#define CONV_THREADS 128

// ---------------- conv tower (per sample,station block) ----------------

template<int CIN, int COUT, int L>
__device__ inline void conv_stage(const float* __restrict__ in, float* __restrict__ out,
                                  const float* __restrict__ w, const float* __restrict__ bias,
                                  int tid) {
  constexpr int NCH = (L + 3) / 4;
  constexpr int ITEMS = COUT * NCH;
  for (int idx = tid; idx < ITEMS; idx += CONV_THREADS) {
    int o = idx / NCH;
    int ch = idx - o * NCH;
    int l0 = ch * 4;
    float b = bias[o];
    float acc0 = b, acc1 = b, acc2 = b, acc3 = b;
    const float* wbase = w + o * CIN * 5;
#pragma unroll
    for (int i = 0; i < CIN; ++i) {
      const float* xi = in + i * L;
      float win[8];
#pragma unroll
      for (int t = 0; t < 8; ++t) {
        int ll = l0 - 2 + t;
        win[t] = (ll >= 0 && ll < L) ? xi[ll] : 0.f;
      }
      const float* wi = wbase + i * 5;
      float w0 = wi[0], w1 = wi[1], w2 = wi[2], w3 = wi[3], w4 = wi[4];
      acc0 += win[0]*w0 + win[1]*w1 + win[2]*w2 + win[3]*w3 + win[4]*w4;
      acc1 += win[1]*w0 + win[2]*w1 + win[3]*w2 + win[4]*w3 + win[5]*w4;
      acc2 += win[2]*w0 + win[3]*w1 + win[4]*w2 + win[5]*w3 + win[6]*w4;
      acc3 += win[3]*w0 + win[4]*w1 + win[5]*w2 + win[6]*w3 + win[7]*w4;
    }
    out[o*L + l0] = fmaxf(acc0, 0.f);
    if (l0+1 < L) out[o*L + l0+1] = fmaxf(acc1, 0.f);
    if (l0+2 < L) out[o*L + l0+2] = fmaxf(acc2, 0.f);
    if (l0+3 < L) out[o*L + l0+3] = fmaxf(acc3, 0.f);
  }
}

template<int C, int LIN, int LOUT>
__device__ inline void pool_stage(const float* __restrict__ in, float* __restrict__ out, int tid) {
  constexpr int ITEMS = C * LOUT;
  for (int idx = tid; idx < ITEMS; idx += CONV_THREADS) {
    int c = idx / LOUT;
    int lo = idx - c * LOUT;
    const float* p = in + c*LIN + 2*lo;
    float m = p[0];
    m = fmaxf(m, p[1]); m = fmaxf(m, p[2]); m = fmaxf(m, p[3]); m = fmaxf(m, p[4]);
    out[c*LOUT + lo] = m;
  }
}

// h0 layout: (4096, 3072), cols 0..2969 = feat in (s,c,l) order (s*297 + c*27 + l),
// cols 2970..3064 = x_train, cols 3065..3071 = zero pad.
__global__ __launch_bounds__(CONV_THREADS) void conv_net_kernel(
    const float* __restrict__ meteo,
    const float* __restrict__ cw1, const float* __restrict__ cb1,
    const float* __restrict__ cw2, const float* __restrict__ cb2,
    const float* __restrict__ cw3, const float* __restrict__ cb3,
    const float* __restrict__ cw4, const float* __restrict__ cb4,
    const float* __restrict__ cw5, const float* __restrict__ cb5,
    const float* __restrict__ cw6, const float* __restrict__ cb6,
    float* __restrict__ h0)
{
  __shared__ float wl[1320];
  __shared__ float bl[42];
  __shared__ float bufA[1185];
  __shared__ float bufB[819];

  const int tid = threadIdx.x;
  const int blk = blockIdx.x;
  const int s = blk % 10;
  const int b = blk / 10;

  // station weights -> LDS (layer offsets: 0,15,90,265,510,825; total 1320)
  for (int i = tid; i < 15;  i += CONV_THREADS) wl[i]     = cw1[s*15  + i];
  for (int i = tid; i < 75;  i += CONV_THREADS) wl[15+i]  = cw2[s*75  + i];
  for (int i = tid; i < 175; i += CONV_THREADS) wl[90+i]  = cw3[s*175 + i];
  for (int i = tid; i < 245; i += CONV_THREADS) wl[265+i] = cw4[s*245 + i];
  for (int i = tid; i < 315; i += CONV_THREADS) wl[510+i] = cw5[s*315 + i];
  for (int i = tid; i < 495; i += CONV_THREADS) wl[825+i] = cw6[s*495 + i];
  if (tid < 3)  bl[tid]      = cb1[s*3  + tid];
  if (tid < 5)  bl[3  + tid] = cb2[s*5  + tid];
  if (tid < 7)  bl[8  + tid] = cb3[s*7  + tid];
  if (tid < 7)  bl[15 + tid] = cb4[s*7  + tid];
  if (tid < 9)  bl[22 + tid] = cb5[s*9  + tid];
  if (tid < 11) bl[31 + tid] = cb6[s*11 + tid];

  // input column for this station: meteo[b, l, s]
  for (int l = tid; l < 237; l += CONV_THREADS)
    bufA[l] = meteo[((size_t)b*237 + l)*10 + s];
  __syncthreads();

  conv_stage<1,3,237>(bufA, bufB, wl+0,   bl+0,  tid); __syncthreads();
  conv_stage<3,5,237>(bufB, bufA, wl+15,  bl+3,  tid); __syncthreads();
  pool_stage<5,237,117>(bufA, bufB, tid);              __syncthreads();
  conv_stage<5,7,117>(bufB, bufA, wl+90,  bl+8,  tid); __syncthreads();
  conv_stage<7,7,117>(bufA, bufB, wl+265, bl+15, tid); __syncthreads();
  pool_stage<7,117,57>(bufB, bufA, tid);               __syncthreads();
  conv_stage<7,9,57>(bufA, bufB, wl+510,  bl+22, tid); __syncthreads();
  conv_stage<9,11,57>(bufB, bufA, wl+825, bl+31, tid); __syncthreads();

  // pool3 (57 -> 27) fused with global write, contiguous 297 floats per block
  float* orow = h0 + (size_t)b*3072 + s*297;
  for (int idx = tid; idx < 297; idx += CONV_THREADS) {
    int c = idx / 27;
    int lo = idx - c*27;
    const float* p = bufA + c*57 + 2*lo;
    float m = p[0];
    m = fmaxf(m, p[1]); m = fmaxf(m, p[2]); m = fmaxf(m, p[3]); m = fmaxf(m, p[4]);
    orow[c*27 + lo] = m;
  }
}

__global__ void pack_xtrain_kernel(const float* __restrict__ xt, float* __restrict__ h0) {
  int b = blockIdx.x;
  int j = threadIdx.x; // 128 threads
  if (j < 102) {
    h0[(size_t)b*3072 + 2970 + j] = (j < 95) ? xt[(size_t)b*95 + j] : 0.f;
  }
}

// ---------------- fp32 tiled GEMM with fused bias+ReLU ----------------
// C[M,N] = relu(A[M,K] @ B[K,N] + bias); A row-major lda, B row-major ldb.
// PERM: B row index permuted (h0 (s,c,l) feat order -> W1 (c,l,s) row order).

__device__ inline int perm_row(int k) {
  if (k < 2970) {
    int s = k / 297;
    int r = k - s*297;
    int c = r / 27;
    int l = r - c*27;
    return (c*27 + l)*10 + s;
  }
  return k;
}

template<bool PERM>
__global__ __launch_bounds__(256) void gemm_bias_relu(
    const float* __restrict__ A, int lda,
    const float* __restrict__ B, int ldb,
    const float* __restrict__ bias,
    float* __restrict__ C, int ldc,
    int N, int K)
{
  __shared__ float As[16][128];  // transposed: As[k][m]
  __shared__ float Bs[16][128];  // Bs[k][n]

  const int tid = threadIdx.x;
  const int tx = tid & 15;   // n-group
  const int ty = tid >> 4;   // m-group
  const int m0 = blockIdx.y * 128;
  const int n0 = blockIdx.x * 128;

  float acc[8][8];
#pragma unroll
  for (int i = 0; i < 8; ++i)
#pragma unroll
    for (int j = 0; j < 8; ++j) acc[i][j] = 0.f;

  const int ktiles = (K + 15) >> 4;
  for (int kt = 0; kt < ktiles; ++kt) {
    const int k0 = kt << 4;
    __syncthreads();
    // stage A tile: 128 rows x 16 k (float4 along k; lda is multiple of 4, so aligned)
#pragma unroll
    for (int ph = 0; ph < 2; ++ph) {
      int idx = tid + ph*256;
      int row = idx >> 2;
      int kq  = (idx & 3) << 2;
      const float* src = A + (size_t)(m0 + row) * lda + k0 + kq;
      float4 v = *reinterpret_cast<const float4*>(src);
      As[kq+0][row] = v.x; As[kq+1][row] = v.y; As[kq+2][row] = v.z; As[kq+3][row] = v.w;
    }
    // stage B tile: 16 k-rows x 128 n
#pragma unroll
    for (int ph = 0; ph < 2; ++ph) {
      int idx = tid + ph*256;
      int krow = idx >> 5;
      int nq = (idx & 31) << 2;
      int kg = k0 + krow;
      int n = n0 + nq;
      float4 v = make_float4(0.f, 0.f, 0.f, 0.f);
      if (kg < K) {
        int ksrc = PERM ? perm_row(kg) : kg;
        const float* src = B + (size_t)ksrc * ldb + n;
        if (n + 3 < N) {
          v = *reinterpret_cast<const float4*>(src);
        } else {
          if (n   < N) v.x = src[0];
          if (n+1 < N) v.y = src[1];
          if (n+2 < N) v.z = src[2];
          if (n+3 < N) v.w = src[3];
        }
      }
      *reinterpret_cast<float4*>(&Bs[krow][nq]) = v;
    }
    __syncthreads();
    // compute: 8x8 outer product per thread
#pragma unroll
    for (int kk = 0; kk < 16; ++kk) {
      float4 a0 = *reinterpret_cast<const float4*>(&As[kk][ty*8]);
      float4 a1 = *reinterpret_cast<const float4*>(&As[kk][ty*8+4]);
      float4 b0 = *reinterpret_cast<const float4*>(&Bs[kk][tx*8]);
      float4 b1 = *reinterpret_cast<const float4*>(&Bs[kk][tx*8+4]);
      float av[8] = {a0.x,a0.y,a0.z,a0.w,a1.x,a1.y,a1.z,a1.w};
      float bv[8] = {b0.x,b0.y,b0.z,b0.w,b1.x,b1.y,b1.z,b1.w};
#pragma unroll
      for (int i = 0; i < 8; ++i)
#pragma unroll
        for (int j = 0; j < 8; ++j)
          acc[i][j] += av[i] * bv[j];
    }
  }
  // epilogue: bias + relu
  float bvals[8];
#pragma unroll
  for (int j = 0; j < 8; ++j) {
    int n = n0 + tx*8 + j;
    bvals[j] = (n < N) ? bias[n] : 0.f;
  }
#pragma unroll
  for (int i = 0; i < 8; ++i) {
    int m = m0 + ty*8 + i;
    float* crow = C + (size_t)m * ldc + n0 + tx*8;
#pragma unroll
    for (int j = 0; j < 8; ++j) {
      int n = n0 + tx*8 + j;
      if (n < N) crow[j] = fmaxf(acc[i][j] + bvals[j], 0.f);
    }
  }
}

// ---------------- small tail layers ----------------

__global__ __launch_bounds__(256) void mlp4_kernel(const float* __restrict__ h3,
                                                   const float* __restrict__ W4,
                                                   const float* __restrict__ b4,
                                                   float* __restrict__ h4) {
  __shared__ float w[2000];
  __shared__ float bb[20];
  int tid = threadIdx.x;
  for (int i = tid; i < 2000; i += 256) w[i] = W4[i];
  if (tid < 20) bb[tid] = b4[tid];
  __syncthreads();
  int gid = blockIdx.x*256 + tid;
  if (gid < 4096*20) {
    int b = gid / 20;
    int n = gid - b*20;
    const float* x = h3 + (size_t)b*100;
    float acc = bb[n];
#pragma unroll 4
    for (int k = 0; k < 100; ++k) acc += x[k] * w[k*20+n];
    h4[gid] = fmaxf(acc, 0.f);
  }
}

__global__ __launch_bounds__(256) void final_kernel(const float* __restrict__ h4,
                                                    const float* __restrict__ xg,
                                                    const float* __restrict__ Wc,
                                                    const float* __restrict__ bc,
                                                    float* __restrict__ out) {
  int b = blockIdx.x*256 + threadIdx.x;
  if (b < 4096) {
    const float* h = h4 + (size_t)b*20;
    float acc = bc[0] + xg[b]*Wc[20];
#pragma unroll
    for (int j = 0; j < 20; ++j) acc += h[j]*Wc[j];
    out[b] = acc;
  }
}

// ---------------- launch ----------------

extern "C" void kernel_launch(void* const* d_in, const int* in_sizes, int n_in,
                              void* d_out, int out_size, void* d_ws, size_t ws_size,
                              hipStream_t stream) {
  const float* x_train = (const float*)d_in[0];
  const float* meteo   = (const float*)d_in[1];
  const float* xg      = (const float*)d_in[2];
  const float* cw1 = (const float*)d_in[3];  const float* cb1 = (const float*)d_in[4];
  const float* cw2 = (const float*)d_in[5];  const float* cb2 = (const float*)d_in[6];
  const float* cw3 = (const float*)d_in[7];  const float* cb3 = (const float*)d_in[8];
  const float* cw4 = (const float*)d_in[9];  const float* cb4 = (const float*)d_in[10];
  const float* cw5 = (const float*)d_in[11]; const float* cb5 = (const float*)d_in[12];
  const float* cw6 = (const float*)d_in[13]; const float* cb6 = (const float*)d_in[14];
  const float* W1 = (const float*)d_in[15];  const float* b1 = (const float*)d_in[16];
  const float* W2 = (const float*)d_in[17];  const float* b2 = (const float*)d_in[18];
  const float* W3 = (const float*)d_in[19];  const float* b3 = (const float*)d_in[20];
  const float* W4 = (const float*)d_in[21];  const float* b4 = (const float*)d_in[22];
  const float* Wc = (const float*)d_in[23];  const float* bc = (const float*)d_in[24];
  float* out = (float*)d_out;

  // workspace layout (floats):
  //   h1: [0, 6,144,000)                4096x1500
  //   h0: [6,144,000, 18,726,912)       4096x3072  (dead after L1)
  //   h2: aliases h0 region start       4096x800
  //   h3: h2 + 3,276,800                4096x100
  //   h4: h3 + 409,600                  4096x20
  float* ws = (float*)d_ws;
  float* h1 = ws;
  float* h0 = ws + 6144000;
  float* h2 = ws + 6144000;
  float* h3 = ws + 6144000 + 3276800;
  float* h4 = ws + 6144000 + 3276800 + 409600;

  hipLaunchKernelGGL(pack_xtrain_kernel, dim3(4096), dim3(128), 0, stream, x_train, h0);
  hipLaunchKernelGGL(conv_net_kernel, dim3(40960), dim3(CONV_THREADS), 0, stream,
                     meteo, cw1, cb1, cw2, cb2, cw3, cb3, cw4, cb4, cw5, cb5, cw6, cb6, h0);
  hipLaunchKernelGGL((gemm_bias_relu<true>),  dim3(12, 32), dim3(256), 0, stream,
                     h0, 3072, W1, 1500, b1, h1, 1500, 1500, 3065);
  hipLaunchKernelGGL((gemm_bias_relu<false>), dim3(7, 32),  dim3(256), 0, stream,
                     h1, 1500, W2, 800, b2, h2, 800, 800, 1500);
  hipLaunchKernelGGL((gemm_bias_relu<false>), dim3(1, 32),  dim3(256), 0, stream,
                     h2, 800, W3, 100, b3, h3, 100, 100, 800);
  hipLaunchKernelGGL(mlp4_kernel, dim3((4096*20 + 255)/256), dim3(256), 0, stream, h3, W4, b4, h4);
  hipLaunchKernelGGL(final_kernel, dim3((4096 + 255)/256), dim3(256), 0, stream, h4, xg, Wc, bc, out);
}

// Round 2
// 787.997 us; speedup vs baseline: 2.0280x; 2.0280x over previous
//
#include <hip/hip_runtime.h>
#include <hip/hip_bf16.h>
#include <cstddef>

typedef unsigned short u16;
typedef __attribute__((ext_vector_type(8))) short bf16x8;
typedef __attribute__((ext_vector_type(4))) float f32x4;

#define CONV_THREADS 128

// ---------- bf16 helpers (manual RNE, no NaN inputs here) ----------
__device__ __forceinline__ u16 f2bf_rn(float v) {
  union { float f; unsigned int u; } x; x.f = v;
  unsigned int r = x.u + 0x7fffu + ((x.u >> 16) & 1u);
  return (u16)(r >> 16);
}
__device__ __forceinline__ float bf2f(u16 b) {
  union { unsigned int u; float f; } x; x.u = ((unsigned int)b) << 16;
  return x.f;
}
__device__ __forceinline__ void split_bf16(float v, u16& hi, u16& lo) {
  hi = f2bf_rn(v);
  lo = f2bf_rn(v - bf2f(hi));
}

// ---------- global -> LDS direct copy (16B per lane) ----------
__device__ __forceinline__ void gload16(const void* g, void* l) {
  __builtin_amdgcn_global_load_lds(
      (const __attribute__((address_space(1))) void*)g,
      (__attribute__((address_space(3))) void*)l,
      16, 0, 0);
}

// ---------------- conv tower (per sample,station block) ----------------

template<int CIN, int COUT, int L>
__device__ inline void conv_stage(const float* __restrict__ in, float* __restrict__ out,
                                  const float* __restrict__ w, const float* __restrict__ bias,
                                  int tid) {
  constexpr int NCH = (L + 3) / 4;
  constexpr int ITEMS = COUT * NCH;
  for (int idx = tid; idx < ITEMS; idx += CONV_THREADS) {
    int o = idx / NCH;
    int ch = idx - o * NCH;
    int l0 = ch * 4;
    float b = bias[o];
    float acc0 = b, acc1 = b, acc2 = b, acc3 = b;
    const float* wbase = w + o * CIN * 5;
#pragma unroll
    for (int i = 0; i < CIN; ++i) {
      const float* xi = in + i * L;
      float win[8];
#pragma unroll
      for (int t = 0; t < 8; ++t) {
        int ll = l0 - 2 + t;
        win[t] = (ll >= 0 && ll < L) ? xi[ll] : 0.f;
      }
      const float* wi = wbase + i * 5;
      float w0 = wi[0], w1 = wi[1], w2 = wi[2], w3 = wi[3], w4 = wi[4];
      acc0 += win[0]*w0 + win[1]*w1 + win[2]*w2 + win[3]*w3 + win[4]*w4;
      acc1 += win[1]*w0 + win[2]*w1 + win[3]*w2 + win[4]*w3 + win[5]*w4;
      acc2 += win[2]*w0 + win[3]*w1 + win[4]*w2 + win[5]*w3 + win[6]*w4;
      acc3 += win[3]*w0 + win[4]*w1 + win[5]*w2 + win[6]*w3 + win[7]*w4;
    }
    out[o*L + l0] = fmaxf(acc0, 0.f);
    if (l0+1 < L) out[o*L + l0+1] = fmaxf(acc1, 0.f);
    if (l0+2 < L) out[o*L + l0+2] = fmaxf(acc2, 0.f);
    if (l0+3 < L) out[o*L + l0+3] = fmaxf(acc3, 0.f);
  }
}

template<int C, int LIN, int LOUT>
__device__ inline void pool_stage(const float* __restrict__ in, float* __restrict__ out, int tid) {
  constexpr int ITEMS = C * LOUT;
  for (int idx = tid; idx < ITEMS; idx += CONV_THREADS) {
    int c = idx / LOUT;
    int lo = idx - c * LOUT;
    const float* p = in + c*LIN + 2*lo;
    float m = p[0];
    m = fmaxf(m, p[1]); m = fmaxf(m, p[2]); m = fmaxf(m, p[3]); m = fmaxf(m, p[4]);
    out[c*LOUT + lo] = m;
  }
}

// A planes layout: (4096 x 3072) u16 each (hi/lo), cols 0..2969 = feat (s*297+c*27+l),
// cols 2970..3064 = x_train, 3065..3071 zero.
__global__ __launch_bounds__(CONV_THREADS) void conv_net_kernel(
    const float* __restrict__ meteo,
    const float* __restrict__ cw1, const float* __restrict__ cb1,
    const float* __restrict__ cw2, const float* __restrict__ cb2,
    const float* __restrict__ cw3, const float* __restrict__ cb3,
    const float* __restrict__ cw4, const float* __restrict__ cb4,
    const float* __restrict__ cw5, const float* __restrict__ cb5,
    const float* __restrict__ cw6, const float* __restrict__ cb6,
    u16* __restrict__ Ahi, u16* __restrict__ Alo)
{
  __shared__ float wl[1320];
  __shared__ float bl[42];
  __shared__ float bufA[1185];
  __shared__ float bufB[819];

  const int tid = threadIdx.x;
  const int blk = blockIdx.x;
  const int s = blk % 10;
  const int b = blk / 10;

  for (int i = tid; i < 15;  i += CONV_THREADS) wl[i]     = cw1[s*15  + i];
  for (int i = tid; i < 75;  i += CONV_THREADS) wl[15+i]  = cw2[s*75  + i];
  for (int i = tid; i < 175; i += CONV_THREADS) wl[90+i]  = cw3[s*175 + i];
  for (int i = tid; i < 245; i += CONV_THREADS) wl[265+i] = cw4[s*245 + i];
  for (int i = tid; i < 315; i += CONV_THREADS) wl[510+i] = cw5[s*315 + i];
  for (int i = tid; i < 495; i += CONV_THREADS) wl[825+i] = cw6[s*495 + i];
  if (tid < 3)  bl[tid]      = cb1[s*3  + tid];
  if (tid < 5)  bl[3  + tid] = cb2[s*5  + tid];
  if (tid < 7)  bl[8  + tid] = cb3[s*7  + tid];
  if (tid < 7)  bl[15 + tid] = cb4[s*7  + tid];
  if (tid < 9)  bl[22 + tid] = cb5[s*9  + tid];
  if (tid < 11) bl[31 + tid] = cb6[s*11 + tid];

  for (int l = tid; l < 237; l += CONV_THREADS)
    bufA[l] = meteo[((size_t)b*237 + l)*10 + s];
  __syncthreads();

  conv_stage<1,3,237>(bufA, bufB, wl+0,   bl+0,  tid); __syncthreads();
  conv_stage<3,5,237>(bufB, bufA, wl+15,  bl+3,  tid); __syncthreads();
  pool_stage<5,237,117>(bufA, bufB, tid);              __syncthreads();
  conv_stage<5,7,117>(bufB, bufA, wl+90,  bl+8,  tid); __syncthreads();
  conv_stage<7,7,117>(bufA, bufB, wl+265, bl+15, tid); __syncthreads();
  pool_stage<7,117,57>(bufB, bufA, tid);               __syncthreads();
  conv_stage<7,9,57>(bufA, bufB, wl+510,  bl+22, tid); __syncthreads();
  conv_stage<9,11,57>(bufB, bufA, wl+825, bl+31, tid); __syncthreads();

  // pool3 (57 -> 27) fused with split-bf16 global write
  u16* ohi = Ahi + (size_t)b*3072 + s*297;
  u16* olo = Alo + (size_t)b*3072 + s*297;
  for (int idx = tid; idx < 297; idx += CONV_THREADS) {
    int c = idx / 27;
    int lo = idx - c*27;
    const float* p = bufA + c*57 + 2*lo;
    float m = p[0];
    m = fmaxf(m, p[1]); m = fmaxf(m, p[2]); m = fmaxf(m, p[3]); m = fmaxf(m, p[4]);
    u16 h, l2; split_bf16(m, h, l2);
    ohi[c*27 + lo] = h;
    olo[c*27 + lo] = l2;
  }
}

__global__ void pack_xtrain_kernel(const float* __restrict__ xt,
                                   u16* __restrict__ Ahi, u16* __restrict__ Alo) {
  int b = blockIdx.x;
  int j = threadIdx.x; // 128 threads
  if (j < 102) {
    float v = (j < 95) ? xt[(size_t)b*95 + j] : 0.f;
    u16 h, l2; split_bf16(v, h, l2);
    Ahi[(size_t)b*3072 + 2970 + j] = h;
    Alo[(size_t)b*3072 + 2970 + j] = l2;
  }
}

// ---------------- weight split+transpose ----------------
// W: [Ksrc][Nsrc] fp32 -> WT hi/lo: [Np][Kp] u16 (transposed, zero-padded).
// PERM bakes the feat-order -> W1-row permutation into k.

__device__ __forceinline__ int perm_row(int k) {
  if (k < 2970) {
    int s = k / 297;
    int r = k - s*297;
    int c = r / 27;
    int l = r - c*27;
    return (c*27 + l)*10 + s;
  }
  return k;
}

template<bool PERM>
__global__ __launch_bounds__(256) void splitw_kernel(
    const float* __restrict__ W, int Ksrc, int Nsrc,
    u16* __restrict__ WThi, u16* __restrict__ WTlo, int Kp)
{
  __shared__ float tile[32][33];
  const int k0 = blockIdx.x * 32;
  const int n0 = blockIdx.y * 32;
  const int tx = threadIdx.x & 31;
  const int ty = threadIdx.x >> 5;   // 0..7

#pragma unroll
  for (int r = 0; r < 32; r += 8) {
    int k = k0 + ty + r;
    int n = n0 + tx;
    float v = 0.f;
    if (k < Ksrc && n < Nsrc) {
      int ks = PERM ? perm_row(k) : k;
      v = W[(size_t)ks * Nsrc + n];
    }
    tile[ty + r][tx] = v;
  }
  __syncthreads();
#pragma unroll
  for (int r = 0; r < 32; r += 8) {
    int n = n0 + ty + r;
    int k = k0 + tx;
    float v = tile[tx][ty + r];
    u16 h, l2; split_bf16(v, h, l2);
    WThi[(size_t)n * Kp + k] = h;
    WTlo[(size_t)n * Kp + k] = l2;
  }
}

__global__ void padbias_kernel(const float* __restrict__ b, int n,
                               float* __restrict__ out, int np) {
  int i = blockIdx.x * 256 + threadIdx.x;
  if (i < np) out[i] = (i < n) ? b[i] : 0.f;
}

// ---------------- split-bf16 MFMA GEMM ----------------
// C[M x N] = relu(Ahi+Alo @ (Bhi+Blo)^T-stored + bias), 3-pass MFMA.
// A planes: [M][lda] u16 row-major; B planes: [N][ldb] u16 (i.e. W^T).
// Tile 128x128, BK=32, 256 threads = 4 waves (2x2 of 64x64).
// All dims exact multiples of tile (zero-padded upstream) -> no masks.

template<int KSTEPS, bool SPLIT_OUT>
__global__ __launch_bounds__(256, 2) void gemm_mfma(
    const u16* __restrict__ Ahi, const u16* __restrict__ Alo, int lda,
    const u16* __restrict__ Bhi, const u16* __restrict__ Blo, int ldb,
    const float* __restrict__ biasp,
    u16* __restrict__ Chi, u16* __restrict__ Clo,
    float* __restrict__ Cf, int ldc)
{
  __shared__ u16 sAhi[128*32];
  __shared__ u16 sAlo[128*32];
  __shared__ u16 sBhi[128*32];
  __shared__ u16 sBlo[128*32];

  const int t = threadIdx.x;

  // XCD-bijective swizzle (all grids are multiples of 8 blocks)
  const int gx = gridDim.x;
  int flat = blockIdx.y * gx + blockIdx.x;
  int nwg = gx * gridDim.y;
  int cpx = nwg >> 3;
  int id = (flat & 7) * cpx + (flat >> 3);
  int mt = id / gx;
  int nt = id - mt * gx;
  const int m0 = mt * 128;
  const int n0 = nt * 128;

  // staging addressing: thread t covers row t>>2 (and +64), 8 elems at (t&3)*8
  const int rowS = t >> 2;
  const int kb = (t & 3) * 8;
  const u16* pAh = Ahi + (size_t)(m0 + rowS) * lda + kb;
  const u16* pAl = Alo + (size_t)(m0 + rowS) * lda + kb;
  const u16* pBh = Bhi + (size_t)(n0 + rowS) * ldb + kb;
  const u16* pBl = Blo + (size_t)(n0 + rowS) * ldb + kb;
  const size_t sA64 = (size_t)64 * lda;
  const size_t sB64 = (size_t)64 * ldb;

  u16* dAh0 = &sAhi[rowS*32 + kb]; u16* dAh1 = &sAhi[(64+rowS)*32 + kb];
  u16* dAl0 = &sAlo[rowS*32 + kb]; u16* dAl1 = &sAlo[(64+rowS)*32 + kb];
  u16* dBh0 = &sBhi[rowS*32 + kb]; u16* dBh1 = &sBhi[(64+rowS)*32 + kb];
  u16* dBl0 = &sBlo[rowS*32 + kb]; u16* dBl1 = &sBlo[(64+rowS)*32 + kb];

  // fragment addressing
  const int l = t & 63;
  const int w = t >> 6;
  const int wr = w >> 1, wc = w & 1;
  const int fr = l & 15;
  const int fq = l >> 4;
  const int aoff = (wr*64 + fr)*32 + fq*8;
  const int boff = (wc*64 + fr)*32 + fq*8;

  const f32x4 vzero = {0.f, 0.f, 0.f, 0.f};
  f32x4 acc[4][4];
#pragma unroll
  for (int i = 0; i < 4; ++i)
#pragma unroll
    for (int j = 0; j < 4; ++j) acc[i][j] = vzero;

  for (int kt = 0; kt < KSTEPS; ++kt) {
    gload16(pAh, dAh0); gload16(pAh + sA64, dAh1);
    gload16(pAl, dAl0); gload16(pAl + sA64, dAl1);
    gload16(pBh, dBh0); gload16(pBh + sB64, dBh1);
    gload16(pBl, dBl0); gload16(pBl + sB64, dBl1);
    pAh += 32; pAl += 32; pBh += 32; pBl += 32;
    __syncthreads();   // drains vmcnt before reads

    bf16x8 ah[4], al[4], bh[4], bl[4];
#pragma unroll
    for (int i = 0; i < 4; ++i) {
      ah[i] = *(const bf16x8*)&sAhi[aoff + i*512];
      al[i] = *(const bf16x8*)&sAlo[aoff + i*512];
    }
#pragma unroll
    for (int j = 0; j < 4; ++j) {
      bh[j] = *(const bf16x8*)&sBhi[boff + j*512];
      bl[j] = *(const bf16x8*)&sBlo[boff + j*512];
    }
#pragma unroll
    for (int i = 0; i < 4; ++i)
#pragma unroll
      for (int j = 0; j < 4; ++j) {
        acc[i][j] = __builtin_amdgcn_mfma_f32_16x16x32_bf16(ah[i], bh[j], acc[i][j], 0, 0, 0);
        acc[i][j] = __builtin_amdgcn_mfma_f32_16x16x32_bf16(al[i], bh[j], acc[i][j], 0, 0, 0);
        acc[i][j] = __builtin_amdgcn_mfma_f32_16x16x32_bf16(ah[i], bl[j], acc[i][j], 0, 0, 0);
      }
    __syncthreads();   // compute done before next-stage overwrite
  }

  // epilogue: bias + relu (+ optional split write for next layer)
  float bv[4];
#pragma unroll
  for (int j = 0; j < 4; ++j) bv[j] = biasp[n0 + wc*64 + j*16 + fr];
#pragma unroll
  for (int i = 0; i < 4; ++i) {
#pragma unroll
    for (int q = 0; q < 4; ++q) {
      const int m = m0 + wr*64 + i*16 + fq*4 + q;
#pragma unroll
      for (int j = 0; j < 4; ++j) {
        const int n = n0 + wc*64 + j*16 + fr;
        float v = fmaxf(acc[i][j][q] + bv[j], 0.f);
        if (SPLIT_OUT) {
          u16 h, l2; split_bf16(v, h, l2);
          Chi[(size_t)m*ldc + n] = h;
          Clo[(size_t)m*ldc + n] = l2;
        } else {
          Cf[(size_t)m*ldc + n] = v;
        }
      }
    }
  }
}

// ---------------- small tail layers ----------------

__global__ __launch_bounds__(256) void mlp4_kernel(const float* __restrict__ h3,
                                                   const float* __restrict__ W4,
                                                   const float* __restrict__ b4,
                                                   float* __restrict__ h4) {
  __shared__ float w[2000];
  __shared__ float bb[20];
  int tid = threadIdx.x;
  for (int i = tid; i < 2000; i += 256) w[i] = W4[i];
  if (tid < 20) bb[tid] = b4[tid];
  __syncthreads();
  int gid = blockIdx.x*256 + tid;
  if (gid < 4096*20) {
    int b = gid / 20;
    int n = gid - b*20;
    const float* x = h3 + (size_t)b*128;   // h3 row stride = 128 now
    float acc = bb[n];
#pragma unroll 4
    for (int k = 0; k < 100; ++k) acc += x[k] * w[k*20+n];
    h4[gid] = fmaxf(acc, 0.f);
  }
}

__global__ __launch_bounds__(256) void final_kernel(const float* __restrict__ h4,
                                                    const float* __restrict__ xg,
                                                    const float* __restrict__ Wc,
                                                    const float* __restrict__ bc,
                                                    float* __restrict__ out) {
  int b = blockIdx.x*256 + threadIdx.x;
  if (b < 4096) {
    const float* h = h4 + (size_t)b*20;
    float acc = bc[0] + xg[b]*Wc[20];
#pragma unroll
    for (int j = 0; j < 20; ++j) acc += h[j]*Wc[j];
    out[b] = acc;
  }
}

// ---------------- launch ----------------

extern "C" void kernel_launch(void* const* d_in, const int* in_sizes, int n_in,
                              void* d_out, int out_size, void* d_ws, size_t ws_size,
                              hipStream_t stream) {
  const float* x_train = (const float*)d_in[0];
  const float* meteo   = (const float*)d_in[1];
  const float* xg      = (const float*)d_in[2];
  const float* cw1 = (const float*)d_in[3];  const float* cb1 = (const float*)d_in[4];
  const float* cw2 = (const float*)d_in[5];  const float* cb2 = (const float*)d_in[6];
  const float* cw3 = (const float*)d_in[7];  const float* cb3 = (const float*)d_in[8];
  const float* cw4 = (const float*)d_in[9];  const float* cb4 = (const float*)d_in[10];
  const float* cw5 = (const float*)d_in[11]; const float* cb5 = (const float*)d_in[12];
  const float* cw6 = (const float*)d_in[13]; const float* cb6 = (const float*)d_in[14];
  const float* W1 = (const float*)d_in[15];  const float* b1 = (const float*)d_in[16];
  const float* W2 = (const float*)d_in[17];  const float* b2 = (const float*)d_in[18];
  const float* W3 = (const float*)d_in[19];  const float* b3 = (const float*)d_in[20];
  const float* W4 = (const float*)d_in[21];  const float* b4 = (const float*)d_in[22];
  const float* Wc = (const float*)d_in[23];  const float* bc = (const float*)d_in[24];
  float* out = (float*)d_out;

  // ---- workspace layout (bytes), peak ~94.4 MB ----
  // Region A [0, 50331648): Ahi(25165824) + Alo(25165824); dead after GEMM1,
  //   then reused for W2T hi/lo (5505024) + h2 hi/lo (14680064).
  // Region B [50331648, 69206016): W1T hi/lo; dead after GEMM1,
  //   then reused for W3T hi/lo + h3(fp32) + h4(fp32).
  // Region C [69206016, 94371840): h1 hi/lo.
  // bias pads at [94371840, ...): bp1(6144) bp2(3584) bp3(512).
  char* base = (char*)d_ws;
  u16* Ahi   = (u16*)(base);
  u16* Alo   = (u16*)(base + 25165824);
  u16* W1Thi = (u16*)(base + 50331648);
  u16* W1Tlo = (u16*)(base + 59768832);
  u16* h1hi  = (u16*)(base + 69206016);
  u16* h1lo  = (u16*)(base + 81788928);
  float* bp1 = (float*)(base + 94371840);
  float* bp2 = (float*)(base + 94377984);
  float* bp3 = (float*)(base + 94381568);
  // Region A reuse:
  u16* W2Thi = (u16*)(base);
  u16* W2Tlo = (u16*)(base + 2752512);
  u16* h2hi  = (u16*)(base + 5505024);
  u16* h2lo  = (u16*)(base + 12845056);
  // Region B reuse:
  u16* W3Thi = (u16*)(base + 50331648);
  u16* W3Tlo = (u16*)(base + 50561024);
  float* h3  = (float*)(base + 50790400);
  float* h4  = (float*)(base + 52887552);

  // bias pads + W1 split (independent of conv)
  hipLaunchKernelGGL(padbias_kernel, dim3(6),  dim3(256), 0, stream, b1, 1500, bp1, 1536);
  hipLaunchKernelGGL(padbias_kernel, dim3(4),  dim3(256), 0, stream, b2, 800,  bp2, 896);
  hipLaunchKernelGGL(padbias_kernel, dim3(1),  dim3(256), 0, stream, b3, 100,  bp3, 128);
  hipLaunchKernelGGL((splitw_kernel<true>),  dim3(96, 48), dim3(256), 0, stream,
                     W1, 3065, 1500, W1Thi, W1Tlo, 3072);

  // A planes
  hipLaunchKernelGGL(pack_xtrain_kernel, dim3(4096), dim3(128), 0, stream, x_train, Ahi, Alo);
  hipLaunchKernelGGL(conv_net_kernel, dim3(40960), dim3(CONV_THREADS), 0, stream,
                     meteo, cw1, cb1, cw2, cb2, cw3, cb3, cw4, cb4, cw5, cb5, cw6, cb6,
                     Ahi, Alo);

  // L1: 4096 x 1536 x 3072
  hipLaunchKernelGGL((gemm_mfma<96, true>), dim3(12, 32), dim3(256), 0, stream,
                     Ahi, Alo, 3072, W1Thi, W1Tlo, 3072, bp1,
                     h1hi, h1lo, (float*)nullptr, 1536);

  // W2 split (into freed Region A), then L2: 4096 x 896 x 1536
  hipLaunchKernelGGL((splitw_kernel<false>), dim3(48, 28), dim3(256), 0, stream,
                     W2, 1500, 800, W2Thi, W2Tlo, 1536);
  hipLaunchKernelGGL((gemm_mfma<48, true>), dim3(7, 32), dim3(256), 0, stream,
                     h1hi, h1lo, 1536, W2Thi, W2Tlo, 1536, bp2,
                     h2hi, h2lo, (float*)nullptr, 896);

  // W3 split (into freed Region B), then L3: 4096 x 128 x 896 (fp32 out)
  hipLaunchKernelGGL((splitw_kernel<false>), dim3(28, 4), dim3(256), 0, stream,
                     W3, 800, 100, W3Thi, W3Tlo, 896);
  hipLaunchKernelGGL((gemm_mfma<28, false>), dim3(1, 32), dim3(256), 0, stream,
                     h2hi, h2lo, 896, W3Thi, W3Tlo, 896, bp3,
                     (u16*)nullptr, (u16*)nullptr, h3, 128);

  hipLaunchKernelGGL(mlp4_kernel, dim3((4096*20 + 255)/256), dim3(256), 0, stream, h3, W4, b4, h4);
  hipLaunchKernelGGL(final_kernel, dim3((4096 + 255)/256), dim3(256), 0, stream, h4, xg, Wc, bc, out);
}

// Round 3
// 636.514 us; speedup vs baseline: 2.5107x; 1.2380x over previous
//
#include <hip/hip_runtime.h>
#include <hip/hip_bf16.h>
#include <cstddef>

typedef unsigned short u16;
typedef __attribute__((ext_vector_type(8))) short bf16x8;
typedef __attribute__((ext_vector_type(4))) float f32x4;

// ---------- bf16 helpers (manual RNE, no NaN inputs here) ----------
__device__ __forceinline__ u16 f2bf_rn(float v) {
  union { float f; unsigned int u; } x; x.f = v;
  unsigned int r = x.u + 0x7fffu + ((x.u >> 16) & 1u);
  return (u16)(r >> 16);
}
__device__ __forceinline__ float bf2f(u16 b) {
  union { unsigned int u; float f; } x; x.u = ((unsigned int)b) << 16;
  return x.f;
}
__device__ __forceinline__ void split_bf16(float v, u16& hi, u16& lo) {
  hi = f2bf_rn(v);
  lo = f2bf_rn(v - bf2f(hi));
}

__device__ __forceinline__ f32x4 splat4(float v) { f32x4 r = {v, v, v, v}; return r; }
__device__ __forceinline__ f32x4 max4(f32x4 a, f32x4 b) {
  f32x4 r; r[0]=fmaxf(a[0],b[0]); r[1]=fmaxf(a[1],b[1]); r[2]=fmaxf(a[2],b[2]); r[3]=fmaxf(a[3],b[3]); return r;
}
__device__ __forceinline__ f32x4 relu4(f32x4 a) { return max4(a, splat4(0.f)); }

// ---------- global -> LDS direct copy (16B per lane) ----------
__device__ __forceinline__ void gload16(const void* g, void* l) {
  __builtin_amdgcn_global_load_lds(
      (const __attribute__((address_space(1))) void*)g,
      (__attribute__((address_space(3))) void*)l,
      16, 0, 0);
}

// ---------------- batch-vectorized conv tower ----------------
// Block = 8 samples x 1 station. LDS activations: [c][l][8 samp] as f32x4 pairs:
// buf[(c*L + l)*2 + sg], sg in {0,1} = float4 of samples 4sg..4sg+3.

#define CONVV_THREADS 256

// thread-per-(l-strip, sg); o-loop inside (window regs reused across COUT)
template<int CIN, int COUT, int L, int STRIP>
__device__ __forceinline__ void conv_strip(const f32x4* __restrict__ in4, f32x4* __restrict__ out4,
                                           const float* __restrict__ w, const float* __restrict__ bias,
                                           int tid) {
  const int sg = tid & 1;
  const int item = tid >> 1;
  constexpr int NI = (L + STRIP - 1) / STRIP;
  if (item >= NI) return;
  const int l0 = item * STRIP;
  f32x4 acc[COUT][STRIP];
#pragma unroll
  for (int o = 0; o < COUT; ++o) {
    float bo = bias[o];
#pragma unroll
    for (int st = 0; st < STRIP; ++st) acc[o][st] = splat4(bo);
  }
#pragma unroll
  for (int ci = 0; ci < CIN; ++ci) {
    f32x4 win[STRIP + 4];
#pragma unroll
    for (int t = 0; t < STRIP + 4; ++t) {
      int gl = l0 - 2 + t;
      int glc = gl < 0 ? 0 : (gl > L - 1 ? L - 1 : gl);
      f32x4 v = in4[(ci * L + glc) * 2 + sg];
      win[t] = (gl >= 0 && gl < L) ? v : splat4(0.f);
    }
#pragma unroll
    for (int o = 0; o < COUT; ++o) {
      const float* wp = w + (o * CIN + ci) * 5;
      float w0 = wp[0], w1 = wp[1], w2 = wp[2], w3 = wp[3], w4 = wp[4];
#pragma unroll
      for (int st = 0; st < STRIP; ++st)
        acc[o][st] += win[st]*w0 + win[st+1]*w1 + win[st+2]*w2 + win[st+3]*w3 + win[st+4]*w4;
    }
  }
#pragma unroll
  for (int o = 0; o < COUT; ++o)
#pragma unroll
    for (int st = 0; st < STRIP; ++st)
      if (l0 + st < L) out4[(o * L + l0 + st) * 2 + sg] = relu4(acc[o][st]);
}

// thread-per-(l, oh, sg) for small-L stages; computes o in [O0, O0+ON)
template<int CIN, int COUT, int L, int ON>
__device__ __forceinline__ void conv_pos(const f32x4* __restrict__ in4, f32x4* __restrict__ out4,
                                         const float* __restrict__ w, const float* __restrict__ bias,
                                         int l, int sg, int O0) {
  f32x4 acc[ON];
#pragma unroll
  for (int oi = 0; oi < ON; ++oi) acc[oi] = splat4(bias[O0 + oi]);
#pragma unroll
  for (int ci = 0; ci < CIN; ++ci) {
    f32x4 win[5];
#pragma unroll
    for (int t = 0; t < 5; ++t) {
      int gl = l - 2 + t;
      int glc = gl < 0 ? 0 : (gl > L - 1 ? L - 1 : gl);
      f32x4 v = in4[(ci * L + glc) * 2 + sg];
      win[t] = (gl >= 0 && gl < L) ? v : splat4(0.f);
    }
#pragma unroll
    for (int oi = 0; oi < ON; ++oi) {
      const float* wp = w + ((O0 + oi) * CIN + ci) * 5;
      acc[oi] += win[0]*wp[0] + win[1]*wp[1] + win[2]*wp[2] + win[3]*wp[3] + win[4]*wp[4];
    }
  }
#pragma unroll
  for (int oi = 0; oi < ON; ++oi)
    out4[((O0 + oi) * L + l) * 2 + sg] = relu4(acc[oi]);
}

template<int C, int LIN, int LOUT>
__device__ __forceinline__ void pool_v(const f32x4* __restrict__ in4, f32x4* __restrict__ out4, int tid) {
  constexpr int ITEMS = C * LOUT * 2;
  for (int idx = tid; idx < ITEMS; idx += CONVV_THREADS) {
    int sg = idx & 1;
    int r = idx >> 1;
    int c = r / LOUT;
    int lo = r - c * LOUT;
    const f32x4* p = in4 + (c * LIN + 2 * lo) * 2 + sg;
    f32x4 m = p[0];
    m = max4(m, p[2]); m = max4(m, p[4]); m = max4(m, p[6]); m = max4(m, p[8]);
    out4[(c * LOUT + lo) * 2 + sg] = m;
  }
}

// A planes layout: (4096 x 3072) u16 each (hi/lo), cols 0..2969 = feat (s*297+c*27+l),
// cols 2970..3064 = x_train, 3065..3071 zero.
__global__ __launch_bounds__(CONVV_THREADS) void conv_net_kernel(
    const float* __restrict__ meteo,
    const float* __restrict__ cw1, const float* __restrict__ cb1,
    const float* __restrict__ cw2, const float* __restrict__ cb2,
    const float* __restrict__ cw3, const float* __restrict__ cb3,
    const float* __restrict__ cw4, const float* __restrict__ cb4,
    const float* __restrict__ cw5, const float* __restrict__ cb5,
    const float* __restrict__ cw6, const float* __restrict__ cb6,
    u16* __restrict__ Ahi, u16* __restrict__ Alo)
{
  __shared__ f32x4 bufA[2370];   // 37.9 KB
  __shared__ f32x4 bufB[1638];   // 26.2 KB
  __shared__ float wl[1320];
  __shared__ float bl[42];

  const int tid = threadIdx.x;
  const int bid = blockIdx.x;
  const int s = bid % 10;
  const int b0 = (bid / 10) * 8;

  // station weights -> LDS (layer offsets: 0,15,90,265,510,825)
  for (int i = tid; i < 15;  i += CONVV_THREADS) wl[i]     = cw1[s*15  + i];
  for (int i = tid; i < 75;  i += CONVV_THREADS) wl[15+i]  = cw2[s*75  + i];
  for (int i = tid; i < 175; i += CONVV_THREADS) wl[90+i]  = cw3[s*175 + i];
  for (int i = tid; i < 245; i += CONVV_THREADS) wl[265+i] = cw4[s*245 + i];
  for (int i = tid; i < 315; i += CONVV_THREADS) wl[510+i] = cw5[s*315 + i];
  for (int i = tid; i < 495; i += CONVV_THREADS) wl[825+i] = cw6[s*495 + i];
  if (tid < 3)  bl[tid]      = cb1[s*3  + tid];
  if (tid < 5)  bl[3  + tid] = cb2[s*5  + tid];
  if (tid < 7)  bl[8  + tid] = cb3[s*7  + tid];
  if (tid < 7)  bl[15 + tid] = cb4[s*7  + tid];
  if (tid < 9)  bl[22 + tid] = cb5[s*9  + tid];
  if (tid < 11) bl[31 + tid] = cb6[s*11 + tid];

  // input: bufA[l*2+sg][k] = meteo[b0+sg*4+k][l][s]
  for (int idx = tid; idx < 237*2; idx += CONVV_THREADS) {
    int sg = idx & 1;
    int l = idx >> 1;
    f32x4 v;
#pragma unroll
    for (int k = 0; k < 4; ++k)
      v[k] = meteo[((size_t)(b0 + sg*4 + k)*237 + l)*10 + s];
    bufA[idx] = v;
  }
  __syncthreads();

  conv_strip<1,3,237,2>(bufA, bufB, wl+0,   bl+0,  tid); __syncthreads();
  conv_strip<3,5,237,2>(bufB, bufA, wl+15,  bl+3,  tid); __syncthreads();
  pool_v<5,237,117>(bufA, bufB, tid);                    __syncthreads();
  conv_strip<5,7,117,1>(bufB, bufA, wl+90,  bl+8,  tid); __syncthreads();
  conv_strip<7,7,117,1>(bufA, bufB, wl+265, bl+15, tid); __syncthreads();
  pool_v<7,117,57>(bufB, bufA, tid);                     __syncthreads();
  // L5: 7->9 at L=57, COUT split across oh (overlap at o=4 is a benign dup)
  {
    const int sg = tid & 1, oh = (tid >> 1) & 1, l = tid >> 2;
    if (l < 57) conv_pos<7,9,57,5>(bufA, bufB, wl+510, bl+22, l, sg, oh ? 4 : 0);
  }
  __syncthreads();
  // L6: 9->11 at L=57 (overlap at o=5)
  {
    const int sg = tid & 1, oh = (tid >> 1) & 1, l = tid >> 2;
    if (l < 57) conv_pos<9,11,57,6>(bufB, bufA, wl+825, bl+31, l, sg, oh ? 5 : 0);
  }
  __syncthreads();
  // pool3 (57 -> 27) + split-bf16 global write
  for (int idx = tid; idx < 297*2; idx += CONVV_THREADS) {
    int sg = idx & 1;
    int r = idx >> 1;
    int c = r / 27;
    int lo = r - c*27;
    const f32x4* p = bufA + (c*57 + 2*lo)*2 + sg;
    f32x4 m = p[0];
    m = max4(m, p[2]); m = max4(m, p[4]); m = max4(m, p[6]); m = max4(m, p[8]);
#pragma unroll
    for (int k = 0; k < 4; ++k) {
      u16 h, l2; split_bf16(m[k], h, l2);
      size_t off = (size_t)(b0 + sg*4 + k)*3072 + s*297 + c*27 + lo;
      Ahi[off] = h; Alo[off] = l2;
    }
  }
}

__global__ void pack_xtrain_kernel(const float* __restrict__ xt,
                                   u16* __restrict__ Ahi, u16* __restrict__ Alo) {
  int b = blockIdx.x;
  int j = threadIdx.x; // 128 threads
  if (j < 102) {
    float v = (j < 95) ? xt[(size_t)b*95 + j] : 0.f;
    u16 h, l2; split_bf16(v, h, l2);
    Ahi[(size_t)b*3072 + 2970 + j] = h;
    Alo[(size_t)b*3072 + 2970 + j] = l2;
  }
}

// ---------------- weight split+transpose ----------------

__device__ __forceinline__ int perm_row(int k) {
  if (k < 2970) {
    int s = k / 297;
    int r = k - s*297;
    int c = r / 27;
    int l = r - c*27;
    return (c*27 + l)*10 + s;
  }
  return k;
}

template<bool PERM>
__global__ __launch_bounds__(256) void splitw_kernel(
    const float* __restrict__ W, int Ksrc, int Nsrc,
    u16* __restrict__ WThi, u16* __restrict__ WTlo, int Kp)
{
  __shared__ float tile[32][33];
  const int k0 = blockIdx.x * 32;
  const int n0 = blockIdx.y * 32;
  const int tx = threadIdx.x & 31;
  const int ty = threadIdx.x >> 5;   // 0..7

#pragma unroll
  for (int r = 0; r < 32; r += 8) {
    int k = k0 + ty + r;
    int n = n0 + tx;
    float v = 0.f;
    if (k < Ksrc && n < Nsrc) {
      int ks = PERM ? perm_row(k) : k;
      v = W[(size_t)ks * Nsrc + n];
    }
    tile[ty + r][tx] = v;
  }
  __syncthreads();
#pragma unroll
  for (int r = 0; r < 32; r += 8) {
    int n = n0 + ty + r;
    int k = k0 + tx;
    float v = tile[tx][ty + r];
    u16 h, l2; split_bf16(v, h, l2);
    WThi[(size_t)n * Kp + k] = h;
    WTlo[(size_t)n * Kp + k] = l2;
  }
}

__global__ void padbias_kernel(const float* __restrict__ b, int n,
                               float* __restrict__ out, int np) {
  int i = blockIdx.x * 256 + threadIdx.x;
  if (i < np) out[i] = (i < n) ? b[i] : 0.f;
}

// ---------------- split-bf16 MFMA GEMM ----------------
// Tile 128x128, BK=32, 256 threads = 4 waves (2x2 of 64x64), 3-pass split-bf16.

template<int KSTEPS, bool SPLIT_OUT>
__global__ __launch_bounds__(256, 2) void gemm_mfma(
    const u16* __restrict__ Ahi, const u16* __restrict__ Alo, int lda,
    const u16* __restrict__ Bhi, const u16* __restrict__ Blo, int ldb,
    const float* __restrict__ biasp,
    u16* __restrict__ Chi, u16* __restrict__ Clo,
    float* __restrict__ Cf, int ldc)
{
  __shared__ u16 sAhi[128*32];
  __shared__ u16 sAlo[128*32];
  __shared__ u16 sBhi[128*32];
  __shared__ u16 sBlo[128*32];

  const int t = threadIdx.x;

  // XCD-bijective swizzle (all grids are multiples of 8 blocks)
  const int gx = gridDim.x;
  int flat = blockIdx.y * gx + blockIdx.x;
  int nwg = gx * gridDim.y;
  int cpx = nwg >> 3;
  int id = (flat & 7) * cpx + (flat >> 3);
  int mt = id / gx;
  int nt = id - mt * gx;
  const int m0 = mt * 128;
  const int n0 = nt * 128;

  const int rowS = t >> 2;
  const int kb = (t & 3) * 8;
  const u16* pAh = Ahi + (size_t)(m0 + rowS) * lda + kb;
  const u16* pAl = Alo + (size_t)(m0 + rowS) * lda + kb;
  const u16* pBh = Bhi + (size_t)(n0 + rowS) * ldb + kb;
  const u16* pBl = Blo + (size_t)(n0 + rowS) * ldb + kb;
  const size_t sA64 = (size_t)64 * lda;
  const size_t sB64 = (size_t)64 * ldb;

  u16* dAh0 = &sAhi[rowS*32 + kb]; u16* dAh1 = &sAhi[(64+rowS)*32 + kb];
  u16* dAl0 = &sAlo[rowS*32 + kb]; u16* dAl1 = &sAlo[(64+rowS)*32 + kb];
  u16* dBh0 = &sBhi[rowS*32 + kb]; u16* dBh1 = &sBhi[(64+rowS)*32 + kb];
  u16* dBl0 = &sBlo[rowS*32 + kb]; u16* dBl1 = &sBlo[(64+rowS)*32 + kb];

  const int l = t & 63;
  const int w = t >> 6;
  const int wr = w >> 1, wc = w & 1;
  const int fr = l & 15;
  const int fq = l >> 4;
  const int aoff = (wr*64 + fr)*32 + fq*8;
  const int boff = (wc*64 + fr)*32 + fq*8;

  const f32x4 vzero = {0.f, 0.f, 0.f, 0.f};
  f32x4 acc[4][4];
#pragma unroll
  for (int i = 0; i < 4; ++i)
#pragma unroll
    for (int j = 0; j < 4; ++j) acc[i][j] = vzero;

  for (int kt = 0; kt < KSTEPS; ++kt) {
    gload16(pAh, dAh0); gload16(pAh + sA64, dAh1);
    gload16(pAl, dAl0); gload16(pAl + sA64, dAl1);
    gload16(pBh, dBh0); gload16(pBh + sB64, dBh1);
    gload16(pBl, dBl0); gload16(pBl + sB64, dBl1);
    pAh += 32; pAl += 32; pBh += 32; pBl += 32;
    __syncthreads();

    bf16x8 ah[4], al[4], bh[4], bl[4];
#pragma unroll
    for (int i = 0; i < 4; ++i) {
      ah[i] = *(const bf16x8*)&sAhi[aoff + i*512];
      al[i] = *(const bf16x8*)&sAlo[aoff + i*512];
    }
#pragma unroll
    for (int j = 0; j < 4; ++j) {
      bh[j] = *(const bf16x8*)&sBhi[boff + j*512];
      bl[j] = *(const bf16x8*)&sBlo[boff + j*512];
    }
#pragma unroll
    for (int i = 0; i < 4; ++i)
#pragma unroll
      for (int j = 0; j < 4; ++j) {
        acc[i][j] = __builtin_amdgcn_mfma_f32_16x16x32_bf16(ah[i], bh[j], acc[i][j], 0, 0, 0);
        acc[i][j] = __builtin_amdgcn_mfma_f32_16x16x32_bf16(al[i], bh[j], acc[i][j], 0, 0, 0);
        acc[i][j] = __builtin_amdgcn_mfma_f32_16x16x32_bf16(ah[i], bl[j], acc[i][j], 0, 0, 0);
      }
    __syncthreads();
  }

  float bv[4];
#pragma unroll
  for (int j = 0; j < 4; ++j) bv[j] = biasp[n0 + wc*64 + j*16 + fr];
#pragma unroll
  for (int i = 0; i < 4; ++i) {
#pragma unroll
    for (int q = 0; q < 4; ++q) {
      const int m = m0 + wr*64 + i*16 + fq*4 + q;
#pragma unroll
      for (int j = 0; j < 4; ++j) {
        const int n = n0 + wc*64 + j*16 + fr;
        float v = fmaxf(acc[i][j][q] + bv[j], 0.f);
        if (SPLIT_OUT) {
          u16 h, l2; split_bf16(v, h, l2);
          Chi[(size_t)m*ldc + n] = h;
          Clo[(size_t)m*ldc + n] = l2;
        } else {
          Cf[(size_t)m*ldc + n] = v;
        }
      }
    }
  }
}

// ---------------- small tail layers ----------------

__global__ __launch_bounds__(256) void mlp4_kernel(const float* __restrict__ h3,
                                                   const float* __restrict__ W4,
                                                   const float* __restrict__ b4,
                                                   float* __restrict__ h4) {
  __shared__ float w[2000];
  __shared__ float bb[20];
  int tid = threadIdx.x;
  for (int i = tid; i < 2000; i += 256) w[i] = W4[i];
  if (tid < 20) bb[tid] = b4[tid];
  __syncthreads();
  int gid = blockIdx.x*256 + tid;
  if (gid < 4096*20) {
    int b = gid / 20;
    int n = gid - b*20;
    const float* x = h3 + (size_t)b*128;   // h3 row stride = 128
    float acc = bb[n];
#pragma unroll 4
    for (int k = 0; k < 100; ++k) acc += x[k] * w[k*20+n];
    h4[gid] = fmaxf(acc, 0.f);
  }
}

__global__ __launch_bounds__(256) void final_kernel(const float* __restrict__ h4,
                                                    const float* __restrict__ xg,
                                                    const float* __restrict__ Wc,
                                                    const float* __restrict__ bc,
                                                    float* __restrict__ out) {
  int b = blockIdx.x*256 + threadIdx.x;
  if (b < 4096) {
    const float* h = h4 + (size_t)b*20;
    float acc = bc[0] + xg[b]*Wc[20];
#pragma unroll
    for (int j = 0; j < 20; ++j) acc += h[j]*Wc[j];
    out[b] = acc;
  }
}

// ---------------- launch ----------------

extern "C" void kernel_launch(void* const* d_in, const int* in_sizes, int n_in,
                              void* d_out, int out_size, void* d_ws, size_t ws_size,
                              hipStream_t stream) {
  const float* x_train = (const float*)d_in[0];
  const float* meteo   = (const float*)d_in[1];
  const float* xg      = (const float*)d_in[2];
  const float* cw1 = (const float*)d_in[3];  const float* cb1 = (const float*)d_in[4];
  const float* cw2 = (const float*)d_in[5];  const float* cb2 = (const float*)d_in[6];
  const float* cw3 = (const float*)d_in[7];  const float* cb3 = (const float*)d_in[8];
  const float* cw4 = (const float*)d_in[9];  const float* cb4 = (const float*)d_in[10];
  const float* cw5 = (const float*)d_in[11]; const float* cb5 = (const float*)d_in[12];
  const float* cw6 = (const float*)d_in[13]; const float* cb6 = (const float*)d_in[14];
  const float* W1 = (const float*)d_in[15];  const float* b1 = (const float*)d_in[16];
  const float* W2 = (const float*)d_in[17];  const float* b2 = (const float*)d_in[18];
  const float* W3 = (const float*)d_in[19];  const float* b3 = (const float*)d_in[20];
  const float* W4 = (const float*)d_in[21];  const float* b4 = (const float*)d_in[22];
  const float* Wc = (const float*)d_in[23];  const float* bc = (const float*)d_in[24];
  float* out = (float*)d_out;

  char* base = (char*)d_ws;
  u16* Ahi   = (u16*)(base);
  u16* Alo   = (u16*)(base + 25165824);
  u16* W1Thi = (u16*)(base + 50331648);
  u16* W1Tlo = (u16*)(base + 59768832);
  u16* h1hi  = (u16*)(base + 69206016);
  u16* h1lo  = (u16*)(base + 81788928);
  float* bp1 = (float*)(base + 94371840);
  float* bp2 = (float*)(base + 94377984);
  float* bp3 = (float*)(base + 94381568);
  u16* W2Thi = (u16*)(base);
  u16* W2Tlo = (u16*)(base + 2752512);
  u16* h2hi  = (u16*)(base + 5505024);
  u16* h2lo  = (u16*)(base + 12845056);
  u16* W3Thi = (u16*)(base + 50331648);
  u16* W3Tlo = (u16*)(base + 50561024);
  float* h3  = (float*)(base + 50790400);
  float* h4  = (float*)(base + 52887552);

  hipLaunchKernelGGL(padbias_kernel, dim3(6),  dim3(256), 0, stream, b1, 1500, bp1, 1536);
  hipLaunchKernelGGL(padbias_kernel, dim3(4),  dim3(256), 0, stream, b2, 800,  bp2, 896);
  hipLaunchKernelGGL(padbias_kernel, dim3(1),  dim3(256), 0, stream, b3, 100,  bp3, 128);
  hipLaunchKernelGGL((splitw_kernel<true>),  dim3(96, 48), dim3(256), 0, stream,
                     W1, 3065, 1500, W1Thi, W1Tlo, 3072);

  hipLaunchKernelGGL(pack_xtrain_kernel, dim3(4096), dim3(128), 0, stream, x_train, Ahi, Alo);
  hipLaunchKernelGGL(conv_net_kernel, dim3(5120), dim3(CONVV_THREADS), 0, stream,
                     meteo, cw1, cb1, cw2, cb2, cw3, cb3, cw4, cb4, cw5, cb5, cw6, cb6,
                     Ahi, Alo);

  // L1: 4096 x 1536 x 3072
  hipLaunchKernelGGL((gemm_mfma<96, true>), dim3(12, 32), dim3(256), 0, stream,
                     Ahi, Alo, 3072, W1Thi, W1Tlo, 3072, bp1,
                     h1hi, h1lo, (float*)nullptr, 1536);

  // W2 split, then L2: 4096 x 896 x 1536
  hipLaunchKernelGGL((splitw_kernel<false>), dim3(48, 28), dim3(256), 0, stream,
                     W2, 1500, 800, W2Thi, W2Tlo, 1536);
  hipLaunchKernelGGL((gemm_mfma<48, true>), dim3(7, 32), dim3(256), 0, stream,
                     h1hi, h1lo, 1536, W2Thi, W2Tlo, 1536, bp2,
                     h2hi, h2lo, (float*)nullptr, 896);

  // W3 split, then L3: 4096 x 128 x 896 (fp32 out)
  hipLaunchKernelGGL((splitw_kernel<false>), dim3(28, 4), dim3(256), 0, stream,
                     W3, 800, 100, W3Thi, W3Tlo, 896);
  hipLaunchKernelGGL((gemm_mfma<28, false>), dim3(1, 32), dim3(256), 0, stream,
                     h2hi, h2lo, 896, W3Thi, W3Tlo, 896, bp3,
                     (u16*)nullptr, (u16*)nullptr, h3, 128);

  hipLaunchKernelGGL(mlp4_kernel, dim3((4096*20 + 255)/256), dim3(256), 0, stream, h3, W4, b4, h4);
  hipLaunchKernelGGL(final_kernel, dim3((4096 + 255)/256), dim3(256), 0, stream, h4, xg, Wc, bc, out);
}

// Round 4
// 484.439 us; speedup vs baseline: 3.2989x; 1.3139x over previous
//
#include <hip/hip_runtime.h>
#include <hip/hip_bf16.h>
#include <cstddef>

typedef unsigned short u16;
typedef __attribute__((ext_vector_type(8))) short bf16x8;
typedef __attribute__((ext_vector_type(4))) float f32x4;

// ---------- bf16 helpers (manual RNE, no NaN inputs here) ----------
__device__ __forceinline__ u16 f2bf_rn(float v) {
  union { float f; unsigned int u; } x; x.f = v;
  unsigned int r = x.u + 0x7fffu + ((x.u >> 16) & 1u);
  return (u16)(r >> 16);
}
__device__ __forceinline__ float bf2f(u16 b) {
  union { unsigned int u; float f; } x; x.u = ((unsigned int)b) << 16;
  return x.f;
}
__device__ __forceinline__ void split_bf16(float v, u16& hi, u16& lo) {
  hi = f2bf_rn(v);
  lo = f2bf_rn(v - bf2f(hi));
}

__device__ __forceinline__ f32x4 splat4(float v) { f32x4 r = {v, v, v, v}; return r; }
__device__ __forceinline__ f32x4 max4(f32x4 a, f32x4 b) {
  f32x4 r; r[0]=fmaxf(a[0],b[0]); r[1]=fmaxf(a[1],b[1]); r[2]=fmaxf(a[2],b[2]); r[3]=fmaxf(a[3],b[3]); return r;
}
__device__ __forceinline__ f32x4 relu4(f32x4 a) { return max4(a, splat4(0.f)); }

// ---------- global -> LDS direct copy (16B per lane) ----------
__device__ __forceinline__ void gload16(const void* g, void* l) {
  __builtin_amdgcn_global_load_lds(
      (const __attribute__((address_space(1))) void*)g,
      (__attribute__((address_space(3))) void*)l,
      16, 0, 0);
}

// ---------------- meteo transpose: [b][l][s] -> [s][l][b] ----------------
__global__ __launch_bounds__(256) void transpose_meteo(const float* __restrict__ meteo,
                                                       float* __restrict__ mT) {
  __shared__ float tile[64][65];
  const int ls0 = blockIdx.x * 64;   // over 2370 = 237*10
  const int b0  = blockIdx.y * 64;   // over 4096
  const int tx = threadIdx.x & 63;
  const int ty = threadIdx.x >> 6;   // 0..3
#pragma unroll
  for (int r = 0; r < 64; r += 4) {
    int b = b0 + ty + r;
    int ls = ls0 + tx;
    float v = (ls < 2370) ? meteo[(size_t)b*2370 + ls] : 0.f;
    tile[ty + r][tx] = v;
  }
  __syncthreads();
#pragma unroll
  for (int r = 0; r < 64; r += 4) {
    int ls = ls0 + ty + r;
    if (ls < 2370) {
      int s2 = ls % 10, l = ls / 10;
      mT[((size_t)s2*237 + l)*4096 + b0 + tx] = tile[tx][ty + r];
    }
  }
}

// ---------------- batch-vectorized conv tower (padded LDS rows) ----------------
// Block = 8 samples x 1 station. LDS activations padded: row stride LP=L+4,
// logical l stored at entry (c*LP + l + 2)*2 + sg; entries 0,1 and L+2,L+3 are zeros.

#define CONVV_THREADS 256

template<int COUT, int L>
__device__ __forceinline__ void zero_pads(f32x4* __restrict__ out4, int tid) {
  constexpr int LP = L + 4;
  if (tid < COUT * 8) {
    int c = tid >> 3, q = tid & 7, sg = q & 1, pi = q >> 1;
    int p = (pi < 2) ? pi : (L + pi);   // {0,1,L+2,L+3}
    out4[(c*LP + p)*2 + sg] = splat4(0.f);
  }
}

// thread-per-(l-strip, sg); o-loop inside (window regs reused across COUT)
template<int CIN, int COUT, int L, int STRIP>
__device__ __forceinline__ void conv_strip_p(const f32x4* __restrict__ in4, f32x4* __restrict__ out4,
                                             const float* __restrict__ w8, const float* __restrict__ bias,
                                             int tid) {
  constexpr int LP = L + 4;
  zero_pads<COUT, L>(out4, tid);
  const int sg = tid & 1;
  const int item = tid >> 1;
  constexpr int NI = (L + STRIP - 1) / STRIP;
  if (item < NI) {
    const int l0 = item * STRIP;
    const f32x4* ibase = in4 + l0*2 + sg;
    f32x4 acc[COUT][STRIP];
#pragma unroll
    for (int o = 0; o < COUT; ++o) {
      float bo = bias[o];
#pragma unroll
      for (int st = 0; st < STRIP; ++st) acc[o][st] = splat4(bo);
    }
#pragma unroll
    for (int ci = 0; ci < CIN; ++ci) {
      const f32x4* ip = ibase + ci*LP*2;
      f32x4 win[STRIP + 4];
#pragma unroll
      for (int t = 0; t < STRIP + 4; ++t) win[t] = ip[t*2];   // ds_read_b128, folded offsets
#pragma unroll
      for (int o = 0; o < COUT; ++o) {
        const float* wp = w8 + (o*CIN + ci)*8;
        float4 wv = *reinterpret_cast<const float4*>(wp);
        float w4v = wp[4];
#pragma unroll
        for (int st = 0; st < STRIP; ++st)
          acc[o][st] += win[st]*wv.x + win[st+1]*wv.y + win[st+2]*wv.z + win[st+3]*wv.w + win[st+4]*w4v;
      }
    }
#pragma unroll
    for (int o = 0; o < COUT; ++o)
#pragma unroll
      for (int st = 0; st < STRIP; ++st)
        if (l0 + st < L) out4[(o*LP + l0 + st + 2)*2 + sg] = relu4(acc[o][st]);
  }
}

// thread-per-(l, sg) [optionally o-split]; computes o in [O0, O0+ON)
template<int CIN, int COUT, int L, int ON>
__device__ __forceinline__ void conv_pos_p(const f32x4* __restrict__ in4, f32x4* __restrict__ out4,
                                           const float* __restrict__ w8, const float* __restrict__ bias,
                                           int l, int sg, int O0) {
  constexpr int LP = L + 4;
  f32x4 acc[ON];
#pragma unroll
  for (int oi = 0; oi < ON; ++oi) acc[oi] = splat4(bias[O0 + oi]);
  const f32x4* ibase = in4 + l*2 + sg;
#pragma unroll
  for (int ci = 0; ci < CIN; ++ci) {
    const f32x4* ip = ibase + ci*LP*2;
    f32x4 win[5];
#pragma unroll
    for (int t = 0; t < 5; ++t) win[t] = ip[t*2];
#pragma unroll
    for (int oi = 0; oi < ON; ++oi) {
      const float* wp = w8 + ((O0 + oi)*CIN + ci)*8;
      float4 wv = *reinterpret_cast<const float4*>(wp);
      float w4v = wp[4];
      acc[oi] += win[0]*wv.x + win[1]*wv.y + win[2]*wv.z + win[3]*wv.w + win[4]*w4v;
    }
  }
#pragma unroll
  for (int oi = 0; oi < ON; ++oi)
    out4[((O0 + oi)*LP + l + 2)*2 + sg] = relu4(acc[oi]);
}

template<int C, int LIN, int LOUT>
__device__ __forceinline__ void pool_p(const f32x4* __restrict__ in4, f32x4* __restrict__ out4, int tid) {
  constexpr int LINP = LIN + 4, LOUTP = LOUT + 4;
  zero_pads<C, LOUT>(out4, tid);
  constexpr int ITEMS = C * LOUT * 2;
  for (int idx = tid; idx < ITEMS; idx += CONVV_THREADS) {
    int sg = idx & 1;
    int r = idx >> 1;
    int c = r / LOUT;
    int lo = r - c * LOUT;
    const f32x4* p = in4 + (c*LINP + 2*lo + 2)*2 + sg;
    f32x4 m = max4(max4(max4(p[0], p[2]), max4(p[4], p[6])), p[8]);
    out4[(c*LOUTP + lo + 2)*2 + sg] = m;
  }
}

// A planes layout: (4096 x 3072) u16 each (hi/lo), cols 0..2969 = feat (s*297+c*27+l),
// cols 2970..3064 = x_train, 3065..3071 zero.
__global__ __launch_bounds__(CONVV_THREADS) void conv_net_kernel(
    const float* __restrict__ mT,
    const float* __restrict__ cw1, const float* __restrict__ cb1,
    const float* __restrict__ cw2, const float* __restrict__ cb2,
    const float* __restrict__ cw3, const float* __restrict__ cb3,
    const float* __restrict__ cw4, const float* __restrict__ cb4,
    const float* __restrict__ cw5, const float* __restrict__ cb5,
    const float* __restrict__ cw6, const float* __restrict__ cb6,
    u16* __restrict__ Ahi, u16* __restrict__ Alo)
{
  __shared__ f32x4 bufA[2416];   // 38.7 KB  (max stage 2410 + overread slack)
  __shared__ f32x4 bufB[1700];   // 27.2 KB  (max stage 1694 + slack)
  __shared__ float wl8[2112];    // 8.4 KB, 8-float-padded (o,ci) slots
  __shared__ float bl[42];

  const int tid = threadIdx.x;
  const int bid = blockIdx.x;
  const int s = bid % 10;
  const int b0 = (bid / 10) * 8;

  // station weights -> LDS, padded to 8 floats per (o,ci) pair
#define STAGE_W(cw, sz, off8) \
  for (int i = tid; i < (sz); i += CONVV_THREADS) { int p_ = i/5, k_ = i - p_*5; wl8[(off8) + p_*8 + k_] = cw[s*(sz) + i]; }
  STAGE_W(cw1, 15, 0)
  STAGE_W(cw2, 75, 24)
  STAGE_W(cw3, 175, 144)
  STAGE_W(cw4, 245, 424)
  STAGE_W(cw5, 315, 816)
  STAGE_W(cw6, 495, 1320)
#undef STAGE_W
  if (tid < 3)  bl[tid]      = cb1[s*3  + tid];
  if (tid < 5)  bl[3  + tid] = cb2[s*5  + tid];
  if (tid < 7)  bl[8  + tid] = cb3[s*7  + tid];
  if (tid < 7)  bl[15 + tid] = cb4[s*7  + tid];
  if (tid < 9)  bl[22 + tid] = cb5[s*9  + tid];
  if (tid < 11) bl[31 + tid] = cb6[s*11 + tid];

  // input (padded, CIN=1): bufA[(l+2)*2+sg] <- mT[s][l][b0 + 4sg .. +3]
  if (tid < 8) {
    int sg = tid & 1, pi = tid >> 1;
    int p = (pi < 2) ? pi : (237 + pi);
    bufA[p*2 + sg] = splat4(0.f);
  }
  for (int idx = tid; idx < 474; idx += CONVV_THREADS) {
    int sg = idx & 1;
    int l = idx >> 1;
    bufA[(l + 2)*2 + sg] = *reinterpret_cast<const f32x4*>(&mT[((size_t)s*237 + l)*4096 + b0 + sg*4]);
  }
  __syncthreads();

  conv_strip_p<1,3,237,2>(bufA, bufB, wl8+0,   bl+0,  tid); __syncthreads();
  conv_strip_p<3,5,237,2>(bufB, bufA, wl8+24,  bl+3,  tid); __syncthreads();
  pool_p<5,237,117>(bufA, bufB, tid);                       __syncthreads();
  // L3: 5->7 at L=117, full COUT per thread
  zero_pads<7,117>(bufA, tid);
  { const int sg = tid & 1, l = tid >> 1;
    if (l < 117) conv_pos_p<5,7,117,7>(bufB, bufA, wl8+144, bl+8, l, sg, 0); }
  __syncthreads();
  // L4: 7->7 at L=117
  zero_pads<7,117>(bufB, tid);
  { const int sg = tid & 1, l = tid >> 1;
    if (l < 117) conv_pos_p<7,7,117,7>(bufA, bufB, wl8+424, bl+15, l, sg, 0); }
  __syncthreads();
  pool_p<7,117,57>(bufB, bufA, tid);                        __syncthreads();
  // L5: 7->9 at L=57, COUT split (dup at o=4 is a benign identical write)
  zero_pads<9,57>(bufB, tid);
  { const int sg = tid & 1, oh = (tid >> 1) & 1, l = tid >> 2;
    if (l < 57) conv_pos_p<7,9,57,5>(bufA, bufB, wl8+816, bl+22, l, sg, oh ? 4 : 0); }
  __syncthreads();
  // L6: 9->11 at L=57 (dup at o=5)
  zero_pads<11,57>(bufA, tid);
  { const int sg = tid & 1, oh = (tid >> 1) & 1, l = tid >> 2;
    if (l < 57) conv_pos_p<9,11,57,6>(bufB, bufA, wl8+1320, bl+31, l, sg, oh ? 5 : 0); }
  __syncthreads();
  // pool3 (57 -> 27) + split-bf16 global write; o6 rows padded LP=61
  for (int idx = tid; idx < 594; idx += CONVV_THREADS) {
    int sg = idx & 1;
    int r = idx >> 1;
    int c = r / 27;
    int lo = r - c*27;
    const f32x4* p = bufA + (c*61 + 2*lo + 2)*2 + sg;
    f32x4 m = max4(max4(max4(p[0], p[2]), max4(p[4], p[6])), p[8]);
#pragma unroll
    for (int k = 0; k < 4; ++k) {
      u16 h, l2; split_bf16(m[k], h, l2);
      size_t off = (size_t)(b0 + sg*4 + k)*3072 + s*297 + c*27 + lo;
      Ahi[off] = h; Alo[off] = l2;
    }
  }
}

__global__ void pack_xtrain_kernel(const float* __restrict__ xt,
                                   u16* __restrict__ Ahi, u16* __restrict__ Alo) {
  int b = blockIdx.x;
  int j = threadIdx.x; // 128 threads
  if (j < 102) {
    float v = (j < 95) ? xt[(size_t)b*95 + j] : 0.f;
    u16 h, l2; split_bf16(v, h, l2);
    Ahi[(size_t)b*3072 + 2970 + j] = h;
    Alo[(size_t)b*3072 + 2970 + j] = l2;
  }
}

// ---------------- weight split+transpose ----------------

__device__ __forceinline__ int perm_row(int k) {
  if (k < 2970) {
    int s = k / 297;
    int r = k - s*297;
    int c = r / 27;
    int l = r - c*27;
    return (c*27 + l)*10 + s;
  }
  return k;
}

template<bool PERM>
__global__ __launch_bounds__(256) void splitw_kernel(
    const float* __restrict__ W, int Ksrc, int Nsrc,
    u16* __restrict__ WThi, u16* __restrict__ WTlo, int Kp)
{
  __shared__ float tile[32][33];
  const int k0 = blockIdx.x * 32;
  const int n0 = blockIdx.y * 32;
  const int tx = threadIdx.x & 31;
  const int ty = threadIdx.x >> 5;   // 0..7

#pragma unroll
  for (int r = 0; r < 32; r += 8) {
    int k = k0 + ty + r;
    int n = n0 + tx;
    float v = 0.f;
    if (k < Ksrc && n < Nsrc) {
      int ks = PERM ? perm_row(k) : k;
      v = W[(size_t)ks * Nsrc + n];
    }
    tile[ty + r][tx] = v;
  }
  __syncthreads();
#pragma unroll
  for (int r = 0; r < 32; r += 8) {
    int n = n0 + ty + r;
    int k = k0 + tx;
    float v = tile[tx][ty + r];
    u16 h, l2; split_bf16(v, h, l2);
    WThi[(size_t)n * Kp + k] = h;
    WTlo[(size_t)n * Kp + k] = l2;
  }
}

__global__ void padbias_kernel(const float* __restrict__ b, int n,
                               float* __restrict__ out, int np) {
  int i = blockIdx.x * 256 + threadIdx.x;
  if (i < np) out[i] = (i < n) ? b[i] : 0.f;
}

// ---------------- split-bf16 MFMA GEMM ----------------
// Tile 128x128, BK=32, 256 threads = 4 waves (2x2 of 64x64), 3-pass split-bf16.

template<int KSTEPS, bool SPLIT_OUT>
__global__ __launch_bounds__(256, 2) void gemm_mfma(
    const u16* __restrict__ Ahi, const u16* __restrict__ Alo, int lda,
    const u16* __restrict__ Bhi, const u16* __restrict__ Blo, int ldb,
    const float* __restrict__ biasp,
    u16* __restrict__ Chi, u16* __restrict__ Clo,
    float* __restrict__ Cf, int ldc)
{
  __shared__ u16 sAhi[128*32];
  __shared__ u16 sAlo[128*32];
  __shared__ u16 sBhi[128*32];
  __shared__ u16 sBlo[128*32];

  const int t = threadIdx.x;

  // XCD-bijective swizzle (all grids are multiples of 8 blocks)
  const int gx = gridDim.x;
  int flat = blockIdx.y * gx + blockIdx.x;
  int nwg = gx * gridDim.y;
  int cpx = nwg >> 3;
  int id = (flat & 7) * cpx + (flat >> 3);
  int mt = id / gx;
  int nt = id - mt * gx;
  const int m0 = mt * 128;
  const int n0 = nt * 128;

  const int rowS = t >> 2;
  const int kb = (t & 3) * 8;
  const u16* pAh = Ahi + (size_t)(m0 + rowS) * lda + kb;
  const u16* pAl = Alo + (size_t)(m0 + rowS) * lda + kb;
  const u16* pBh = Bhi + (size_t)(n0 + rowS) * ldb + kb;
  const u16* pBl = Blo + (size_t)(n0 + rowS) * ldb + kb;
  const size_t sA64 = (size_t)64 * lda;
  const size_t sB64 = (size_t)64 * ldb;

  u16* dAh0 = &sAhi[rowS*32 + kb]; u16* dAh1 = &sAhi[(64+rowS)*32 + kb];
  u16* dAl0 = &sAlo[rowS*32 + kb]; u16* dAl1 = &sAlo[(64+rowS)*32 + kb];
  u16* dBh0 = &sBhi[rowS*32 + kb]; u16* dBh1 = &sBhi[(64+rowS)*32 + kb];
  u16* dBl0 = &sBlo[rowS*32 + kb]; u16* dBl1 = &sBlo[(64+rowS)*32 + kb];

  const int l = t & 63;
  const int w = t >> 6;
  const int wr = w >> 1, wc = w & 1;
  const int fr = l & 15;
  const int fq = l >> 4;
  const int aoff = (wr*64 + fr)*32 + fq*8;
  const int boff = (wc*64 + fr)*32 + fq*8;

  const f32x4 vzero = {0.f, 0.f, 0.f, 0.f};
  f32x4 acc[4][4];
#pragma unroll
  for (int i = 0; i < 4; ++i)
#pragma unroll
    for (int j = 0; j < 4; ++j) acc[i][j] = vzero;

  for (int kt = 0; kt < KSTEPS; ++kt) {
    gload16(pAh, dAh0); gload16(pAh + sA64, dAh1);
    gload16(pAl, dAl0); gload16(pAl + sA64, dAl1);
    gload16(pBh, dBh0); gload16(pBh + sB64, dBh1);
    gload16(pBl, dBl0); gload16(pBl + sB64, dBl1);
    pAh += 32; pAl += 32; pBh += 32; pBl += 32;
    __syncthreads();

    bf16x8 ah[4], al[4], bh[4], bl2[4];
#pragma unroll
    for (int i = 0; i < 4; ++i) {
      ah[i] = *(const bf16x8*)&sAhi[aoff + i*512];
      al[i] = *(const bf16x8*)&sAlo[aoff + i*512];
    }
#pragma unroll
    for (int j = 0; j < 4; ++j) {
      bh[j] = *(const bf16x8*)&sBhi[boff + j*512];
      bl2[j] = *(const bf16x8*)&sBlo[boff + j*512];
    }
#pragma unroll
    for (int i = 0; i < 4; ++i)
#pragma unroll
      for (int j = 0; j < 4; ++j) {
        acc[i][j] = __builtin_amdgcn_mfma_f32_16x16x32_bf16(ah[i], bh[j], acc[i][j], 0, 0, 0);
        acc[i][j] = __builtin_amdgcn_mfma_f32_16x16x32_bf16(al[i], bh[j], acc[i][j], 0, 0, 0);
        acc[i][j] = __builtin_amdgcn_mfma_f32_16x16x32_bf16(ah[i], bl2[j], acc[i][j], 0, 0, 0);
      }
    __syncthreads();
  }

  float bv[4];
#pragma unroll
  for (int j = 0; j < 4; ++j) bv[j] = biasp[n0 + wc*64 + j*16 + fr];
#pragma unroll
  for (int i = 0; i < 4; ++i) {
#pragma unroll
    for (int q = 0; q < 4; ++q) {
      const int m = m0 + wr*64 + i*16 + fq*4 + q;
#pragma unroll
      for (int j = 0; j < 4; ++j) {
        const int n = n0 + wc*64 + j*16 + fr;
        float v = fmaxf(acc[i][j][q] + bv[j], 0.f);
        if (SPLIT_OUT) {
          u16 h, l2; split_bf16(v, h, l2);
          Chi[(size_t)m*ldc + n] = h;
          Clo[(size_t)m*ldc + n] = l2;
        } else {
          Cf[(size_t)m*ldc + n] = v;
        }
      }
    }
  }
}

// ---------------- small tail layers ----------------

__global__ __launch_bounds__(256) void mlp4_kernel(const float* __restrict__ h3,
                                                   const float* __restrict__ W4,
                                                   const float* __restrict__ b4,
                                                   float* __restrict__ h4) {
  __shared__ float w[2000];
  __shared__ float bb[20];
  int tid = threadIdx.x;
  for (int i = tid; i < 2000; i += 256) w[i] = W4[i];
  if (tid < 20) bb[tid] = b4[tid];
  __syncthreads();
  int gid = blockIdx.x*256 + tid;
  if (gid < 4096*20) {
    int b = gid / 20;
    int n = gid - b*20;
    const float* x = h3 + (size_t)b*128;   // h3 row stride = 128
    float acc = bb[n];
#pragma unroll 4
    for (int k = 0; k < 100; ++k) acc += x[k] * w[k*20+n];
    h4[gid] = fmaxf(acc, 0.f);
  }
}

__global__ __launch_bounds__(256) void final_kernel(const float* __restrict__ h4,
                                                    const float* __restrict__ xg,
                                                    const float* __restrict__ Wc,
                                                    const float* __restrict__ bc,
                                                    float* __restrict__ out) {
  int b = blockIdx.x*256 + threadIdx.x;
  if (b < 4096) {
    const float* h = h4 + (size_t)b*20;
    float acc = bc[0] + xg[b]*Wc[20];
#pragma unroll
    for (int j = 0; j < 20; ++j) acc += h[j]*Wc[j];
    out[b] = acc;
  }
}

// ---------------- launch ----------------

extern "C" void kernel_launch(void* const* d_in, const int* in_sizes, int n_in,
                              void* d_out, int out_size, void* d_ws, size_t ws_size,
                              hipStream_t stream) {
  const float* x_train = (const float*)d_in[0];
  const float* meteo   = (const float*)d_in[1];
  const float* xg      = (const float*)d_in[2];
  const float* cw1 = (const float*)d_in[3];  const float* cb1 = (const float*)d_in[4];
  const float* cw2 = (const float*)d_in[5];  const float* cb2 = (const float*)d_in[6];
  const float* cw3 = (const float*)d_in[7];  const float* cb3 = (const float*)d_in[8];
  const float* cw4 = (const float*)d_in[9];  const float* cb4 = (const float*)d_in[10];
  const float* cw5 = (const float*)d_in[11]; const float* cb5 = (const float*)d_in[12];
  const float* cw6 = (const float*)d_in[13]; const float* cb6 = (const float*)d_in[14];
  const float* W1 = (const float*)d_in[15];  const float* b1 = (const float*)d_in[16];
  const float* W2 = (const float*)d_in[17];  const float* b2 = (const float*)d_in[18];
  const float* W3 = (const float*)d_in[19];  const float* b3 = (const float*)d_in[20];
  const float* W4 = (const float*)d_in[21];  const float* b4 = (const float*)d_in[22];
  const float* Wc = (const float*)d_in[23];  const float* bc = (const float*)d_in[24];
  float* out = (float*)d_out;

  char* base = (char*)d_ws;
  u16* Ahi   = (u16*)(base);
  u16* Alo   = (u16*)(base + 25165824);
  // meteoT occupies [50331648, 89161728) during conv; region is reused afterwards.
  float* mT  = (float*)(base + 50331648);
  u16* W1Thi = (u16*)(base + 50331648);
  u16* W1Tlo = (u16*)(base + 59768832);
  u16* h1hi  = (u16*)(base + 69206016);
  u16* h1lo  = (u16*)(base + 81788928);
  float* bp1 = (float*)(base + 94371840);
  float* bp2 = (float*)(base + 94377984);
  float* bp3 = (float*)(base + 94381568);
  u16* W2Thi = (u16*)(base);
  u16* W2Tlo = (u16*)(base + 2752512);
  u16* h2hi  = (u16*)(base + 5505024);
  u16* h2lo  = (u16*)(base + 12845056);
  u16* W3Thi = (u16*)(base + 50331648);
  u16* W3Tlo = (u16*)(base + 50561024);
  float* h3  = (float*)(base + 50790400);
  float* h4  = (float*)(base + 52887552);

  // meteo transpose, then conv tower (mT dies after conv; W1T/h1 reuse its space)
  hipLaunchKernelGGL(transpose_meteo, dim3(38, 64), dim3(256), 0, stream, meteo, mT);
  hipLaunchKernelGGL(conv_net_kernel, dim3(5120), dim3(CONVV_THREADS), 0, stream,
                     mT, cw1, cb1, cw2, cb2, cw3, cb3, cw4, cb4, cw5, cb5, cw6, cb6,
                     Ahi, Alo);
  hipLaunchKernelGGL(pack_xtrain_kernel, dim3(4096), dim3(128), 0, stream, x_train, Ahi, Alo);

  // GEMM prep (after conv: overwrites mT region)
  hipLaunchKernelGGL(padbias_kernel, dim3(6),  dim3(256), 0, stream, b1, 1500, bp1, 1536);
  hipLaunchKernelGGL(padbias_kernel, dim3(4),  dim3(256), 0, stream, b2, 800,  bp2, 896);
  hipLaunchKernelGGL(padbias_kernel, dim3(1),  dim3(256), 0, stream, b3, 100,  bp3, 128);
  hipLaunchKernelGGL((splitw_kernel<true>),  dim3(96, 48), dim3(256), 0, stream,
                     W1, 3065, 1500, W1Thi, W1Tlo, 3072);

  // L1: 4096 x 1536 x 3072
  hipLaunchKernelGGL((gemm_mfma<96, true>), dim3(12, 32), dim3(256), 0, stream,
                     Ahi, Alo, 3072, W1Thi, W1Tlo, 3072, bp1,
                     h1hi, h1lo, (float*)nullptr, 1536);

  // W2 split, then L2: 4096 x 896 x 1536
  hipLaunchKernelGGL((splitw_kernel<false>), dim3(48, 28), dim3(256), 0, stream,
                     W2, 1500, 800, W2Thi, W2Tlo, 1536);
  hipLaunchKernelGGL((gemm_mfma<48, true>), dim3(7, 32), dim3(256), 0, stream,
                     h1hi, h1lo, 1536, W2Thi, W2Tlo, 1536, bp2,
                     h2hi, h2lo, (float*)nullptr, 896);

  // W3 split, then L3: 4096 x 128 x 896 (fp32 out)
  hipLaunchKernelGGL((splitw_kernel<false>), dim3(28, 4), dim3(256), 0, stream,
                     W3, 800, 100, W3Thi, W3Tlo, 896);
  hipLaunchKernelGGL((gemm_mfma<28, false>), dim3(1, 32), dim3(256), 0, stream,
                     h2hi, h2lo, 896, W3Thi, W3Tlo, 896, bp3,
                     (u16*)nullptr, (u16*)nullptr, h3, 128);

  hipLaunchKernelGGL(mlp4_kernel, dim3((4096*20 + 255)/256), dim3(256), 0, stream, h3, W4, b4, h4);
  hipLaunchKernelGGL(final_kernel, dim3((4096 + 255)/256), dim3(256), 0, stream, h4, xg, Wc, bc, out);
}